// Round 2
// baseline (1495.212 us; speedup 1.0000x reference)
//
#include <hip/hip_runtime.h>
#include <math.h>

#define N_NODES 50000
#define N_EDGES 1600000
#define SCAN_BS 256
#define N_SCAN_BLOCKS ((N_NODES + SCAN_BS - 1) / SCAN_BS)   // 196

// ---------------- node inverse L2 norm: TPN lanes per node ----------------
template<int F, int TPN>
__global__ void norm_kernel(const float* __restrict__ x, float* __restrict__ nrminv) {
    int gid = blockIdx.x * blockDim.x + threadIdx.x;
    int node = gid / TPN;
    int t = gid % TPN;
    if (node >= N_NODES) return;
    const float* row = x + (size_t)node * F;
    float s = 0.f;
    constexpr int CHUNKS = F / (TPN * 4);
    #pragma unroll
    for (int c = 0; c < CHUNKS; c++) {
        float4 v = *(const float4*)(row + c * TPN * 4 + t * 4);
        s += v.x*v.x + v.y*v.y + v.z*v.z + v.w*v.w;
    }
    #pragma unroll
    for (int m = TPN/2; m >= 1; m >>= 1) s += __shfl_xor(s, m);
    if (t == 0) {
        float n = sqrtf(s);
        nrminv[node] = (n == 0.f) ? 1.f : 1.f / n;
    }
}

// ------------- per-edge cosine sim + threshold + rowsum/deg count -------------
template<int F, int TPE>
__global__ void edge_sim_kernel(const float* __restrict__ x,
                                const float* __restrict__ nrminv,
                                const int* __restrict__ src, const int* __restrict__ dst,
                                float* __restrict__ w_e,
                                float* __restrict__ rowsum, float* __restrict__ degcnt) {
    int gid = blockIdx.x * blockDim.x + threadIdx.x;
    int e = gid / TPE;
    int t = gid % TPE;
    if (e >= N_EDGES) return;
    int s = src[e], d = dst[e];
    const float* rs = x + (size_t)s * F;
    const float* rd = x + (size_t)d * F;
    float acc = 0.f;
    constexpr int CHUNKS = F / (TPE * 4);
    #pragma unroll
    for (int c = 0; c < CHUNKS; c++) {
        float4 a = *(const float4*)(rs + c * TPE * 4 + t * 4);
        float4 b = *(const float4*)(rd + c * TPE * 4 + t * 4);
        acc += a.x*b.x + a.y*b.y + a.z*b.z + a.w*b.w;
    }
    #pragma unroll
    for (int m = TPE/2; m >= 1; m >>= 1) acc += __shfl_xor(acc, m);
    if (t == 0) {
        float sim = acc * nrminv[s] * nrminv[d];
        float w = (s != d && sim >= 0.5f) ? sim : 0.f;
        w_e[e] = w;
        if (w != 0.f) {
            atomicAdd(&rowsum[s], w);     // w >= 0.5 so |w| == w
            atomicAdd(&degcnt[s], 1.f);
        }
    }
}

// ------------- self_w = 1/(deg+1); seed deg2 with self_w -------------
__global__ void selfw_kernel(const float* __restrict__ degcnt,
                             float* __restrict__ selfw, float* __restrict__ deg2) {
    int i = blockIdx.x * blockDim.x + threadIdx.x;
    if (i >= N_NODES) return;
    float sw = 1.f / (degcnt[i] + 1.f);
    selfw[i] = sw;
    deg2[i] = sw;
}

// ------------- L1 row-normalize w; accumulate incoming deg2 at dst -------------
__global__ void edge_norm_kernel(const int* __restrict__ src, const int* __restrict__ dst,
                                 const float* __restrict__ rowsum,
                                 float* __restrict__ w_e, float* __restrict__ deg2) {
    int e = blockIdx.x * blockDim.x + threadIdx.x;
    if (e >= N_EDGES) return;
    float w = w_e[e];
    if (w != 0.f) {
        float wn = w / rowsum[src[e]];   // rowsum >= w > 0 here
        w_e[e] = wn;
        atomicAdd(&deg2[dst[e]], wn);
    }
}

// ------------- dinv = rsqrt(deg2); deg2 > 0 always (self_w > 0) -------------
__global__ void dinv_kernel(const float* __restrict__ deg2, float* __restrict__ dinv) {
    int i = blockIdx.x * blockDim.x + threadIdx.x;
    if (i >= N_NODES) return;
    dinv[i] = rsqrtf(deg2[i]);
}

// ------------- h = x @ W  (W fully LDS-resident; thread computes 4 cols) -------------
template<int FIN, int FOUT>
__global__ void gemm_kernel(const float* __restrict__ x, const float* __restrict__ W,
                            float* __restrict__ h) {
    __shared__ float Wlds[FIN * FOUT];
    for (int i = threadIdx.x; i < FIN * FOUT; i += blockDim.x) Wlds[i] = W[i];
    __syncthreads();
    constexpr int C4 = FOUT / 4;
    int idx = blockIdx.x * blockDim.x + threadIdx.x;
    int row = idx / C4;
    int c4 = idx % C4;
    if (row >= N_NODES) return;
    const float* xr = x + (size_t)row * FIN;
    float4 acc = make_float4(0.f, 0.f, 0.f, 0.f);
    #pragma unroll 4
    for (int k = 0; k < FIN; k++) {
        float xv = xr[k];
        float4 w4 = *(const float4*)&Wlds[k * FOUT + c4 * 4];
        acc.x += xv * w4.x;
        acc.y += xv * w4.y;
        acc.z += xv * w4.z;
        acc.w += xv * w4.w;
    }
    *(float4*)&h[(size_t)row * FOUT + c4 * 4] = acc;
}

// =================== CSR-by-dst build (once per call; graph is layer-invariant) ===================
__global__ void hist_kernel(const int* __restrict__ dst, int* __restrict__ cnt) {
    int e = blockIdx.x * blockDim.x + threadIdx.x;
    if (e < N_EDGES) atomicAdd(&cnt[dst[e]], 1);
}

__global__ void scan1_kernel(const int* __restrict__ cnt, int* __restrict__ partial,
                             int* __restrict__ blocksum) {
    __shared__ int lds[SCAN_BS];
    int i = blockIdx.x * SCAN_BS + threadIdx.x;
    int v = (i < N_NODES) ? cnt[i] : 0;
    lds[threadIdx.x] = v;
    __syncthreads();
    for (int off = 1; off < SCAN_BS; off <<= 1) {
        int add = (threadIdx.x >= off) ? lds[threadIdx.x - off] : 0;
        __syncthreads();
        lds[threadIdx.x] += add;
        __syncthreads();
    }
    if (i < N_NODES) partial[i] = lds[threadIdx.x] - v;        // exclusive
    if (threadIdx.x == SCAN_BS - 1) blocksum[blockIdx.x] = lds[threadIdx.x];
}

__global__ void scan2_kernel(int* __restrict__ blocksum) {
    __shared__ int lds[SCAN_BS];
    int v = (threadIdx.x < N_SCAN_BLOCKS) ? blocksum[threadIdx.x] : 0;
    lds[threadIdx.x] = v;
    __syncthreads();
    for (int off = 1; off < SCAN_BS; off <<= 1) {
        int add = (threadIdx.x >= off) ? lds[threadIdx.x - off] : 0;
        __syncthreads();
        lds[threadIdx.x] += add;
        __syncthreads();
    }
    if (threadIdx.x < N_SCAN_BLOCKS) blocksum[threadIdx.x] = lds[threadIdx.x] - v;  // exclusive
}

__global__ void scan3_kernel(const int* __restrict__ partial, const int* __restrict__ blocksum,
                             int* __restrict__ row_start, int* __restrict__ cursor) {
    int i = blockIdx.x * blockDim.x + threadIdx.x;
    if (i < N_NODES) {
        int rs = partial[i] + blocksum[i / SCAN_BS];
        row_start[i] = rs;
        cursor[i] = rs;
    }
    if (i == N_NODES) row_start[N_NODES] = N_EDGES;
}

__global__ void fill_kernel(const int* __restrict__ dst, int* __restrict__ cursor,
                            int* __restrict__ csr_eid) {
    int e = blockIdx.x * blockDim.x + threadIdx.x;
    if (e < N_EDGES) {
        int pos = atomicAdd(&cursor[dst[e]], 1);
        csr_eid[pos] = e;
    }
}

// ------------- gather conv: out[v] = sum_{e: dst=v} dinv[s]*w*dinv[v]*h[s]
//               + selfw[v]*dinv[v]^2*h[v] + b  (+ReLU). No atomics, 1 write. -------------
template<int FOUT, int TPN, bool RELU>
__global__ void conv_gather_kernel(const int* __restrict__ row_start,
                                   const int* __restrict__ csr_eid,
                                   const int* __restrict__ src,
                                   const float* __restrict__ w_e,
                                   const float* __restrict__ dinv,
                                   const float* __restrict__ selfw,
                                   const float* __restrict__ h,
                                   const float* __restrict__ b,
                                   float* __restrict__ out) {
    int gid = blockIdx.x * blockDim.x + threadIdx.x;
    int node = gid / TPN;
    int t = gid % TPN;
    if (node >= N_NODES) return;
    constexpr int CPL = (FOUT + TPN - 1) / TPN;
    float acc[CPL];
    #pragma unroll
    for (int k = 0; k < CPL; k++) acc[k] = 0.f;
    int beg = row_start[node], end = row_start[node + 1];
    float dv = dinv[node];
    for (int i = beg; i < end; i++) {
        int eid = csr_eid[i];
        float w = w_e[eid];
        if (w == 0.f) continue;
        int s = src[eid];
        float coeff = dinv[s] * w * dv;
        const float* hs = h + (size_t)s * FOUT;
        #pragma unroll
        for (int k = 0; k < CPL; k++) {
            int c = t + k * TPN;
            if (FOUT % TPN == 0 || c < FOUT) acc[k] += coeff * hs[c];
        }
    }
    float sw = selfw[node] * dv * dv;
    const float* hv = h + (size_t)node * FOUT;
    #pragma unroll
    for (int k = 0; k < CPL; k++) {
        int c = t + k * TPN;
        if (FOUT % TPN == 0 || c < FOUT) {
            float v = acc[k] + sw * hv[c] + b[c];
            if (RELU) v = fmaxf(v, 0.f);
            out[(size_t)node * FOUT + c] = v;
        }
    }
}

// ------------- log_softmax over 40 classes: one wave per row -------------
__global__ void logsoftmax_kernel(const float* __restrict__ in, float* __restrict__ out) {
    int gid = blockIdx.x * blockDim.x + threadIdx.x;
    int row = gid / 64;
    int lane = threadIdx.x % 64;
    if (row >= N_NODES) return;
    const float* r = in + (size_t)row * 40;
    float v = (lane < 40) ? r[lane] : -INFINITY;
    float m = v;
    #pragma unroll
    for (int s = 32; s >= 1; s >>= 1) m = fmaxf(m, __shfl_xor(m, s));
    float ex = (lane < 40) ? expf(v - m) : 0.f;
    float sum = ex;
    #pragma unroll
    for (int s = 32; s >= 1; s >>= 1) sum += __shfl_xor(sum, s);
    float lse = m + logf(sum);
    if (lane < 40) out[(size_t)row * 40 + lane] = v - lse;
}

// =================== host orchestration ===================
template<int FIN, int FOUT, int TPN, int TPE_SIM, int TPN_CONV, bool RELU>
static void run_layer(const float* x, const int* src, const int* dst,
                      const float* W, const float* b,
                      float* out, float* h, float* w_e,
                      float* nrminv, float* rowsum, float* degcnt,
                      float* deg2, float* dinv, float* selfw,
                      const int* row_start, const int* csr_eid,
                      hipStream_t stream) {
    const int BS = 256;
    hipMemsetAsync(rowsum, 0, N_NODES * sizeof(float), stream);
    hipMemsetAsync(degcnt, 0, N_NODES * sizeof(float), stream);

    norm_kernel<FIN, TPN><<<(N_NODES * TPN + BS - 1) / BS, BS, 0, stream>>>(x, nrminv);

    long sim_threads = (long)N_EDGES * TPE_SIM;
    edge_sim_kernel<FIN, TPE_SIM><<<(int)((sim_threads + BS - 1) / BS), BS, 0, stream>>>(
        x, nrminv, src, dst, w_e, rowsum, degcnt);

    selfw_kernel<<<(N_NODES + BS - 1) / BS, BS, 0, stream>>>(degcnt, selfw, deg2);

    edge_norm_kernel<<<(N_EDGES + BS - 1) / BS, BS, 0, stream>>>(src, dst, rowsum, w_e, deg2);

    dinv_kernel<<<(N_NODES + BS - 1) / BS, BS, 0, stream>>>(deg2, dinv);

    gemm_kernel<FIN, FOUT><<<(N_NODES * (FOUT / 4) + BS - 1) / BS, BS, 0, stream>>>(x, W, h);

    long conv_threads = (long)N_NODES * TPN_CONV;
    conv_gather_kernel<FOUT, TPN_CONV, RELU><<<(int)((conv_threads + BS - 1) / BS), BS, 0, stream>>>(
        row_start, csr_eid, src, w_e, dinv, selfw, h, b, out);
}

extern "C" void kernel_launch(void* const* d_in, const int* in_sizes, int n_in,
                              void* d_out, int out_size, void* d_ws, size_t ws_size,
                              hipStream_t stream) {
    const float* x0 = (const float*)d_in[0];
    const int* ei   = (const int*)d_in[1];
    const int* src  = ei;
    const int* dst  = ei + N_EDGES;
    const float* W1 = (const float*)d_in[2];
    const float* b1 = (const float*)d_in[3];
    const float* W2 = (const float*)d_in[4];
    const float* b2 = (const float*)d_in[5];
    const float* W3 = (const float*)d_in[6];
    const float* b3 = (const float*)d_in[7];
    float* out = (float*)d_out;

    // workspace layout: ~17.5M floats + ~1.75M ints ≈ 77 MB
    float* ws     = (float*)d_ws;
    float* xbuf1  = ws;                        // 50000*128 = 6,400,000
    float* h      = xbuf1 + 6400000;           // 6,400,000
    float* w_e    = h + 6400000;               // 1,600,000
    float* xbuf2  = w_e + 1600000;             // 800,000
    float* tmp3   = xbuf2 + 800000;            // 2,000,000
    float* nrminv = tmp3 + 2000000;            // 50,000
    float* rowsum = nrminv + 50000;
    float* degcnt = rowsum + 50000;
    float* deg2   = degcnt + 50000;
    float* dinv   = deg2 + 50000;
    float* selfw  = dinv + 50000;
    int* iws       = (int*)(selfw + 50000);
    int* row_start = iws;                      // 50001
    int* cursor    = row_start + 50001;        // 50000 (doubles as cnt)
    int* partial   = cursor + 50001;           // 50000
    int* blocksum  = partial + 50000;          // 256
    int* csr_eid   = blocksum + 256;           // 1,600,000

    const int BS = 256;

    // ---- build CSR by dst (structure only; reused by all 3 layers) ----
    hipMemsetAsync(cursor, 0, N_NODES * sizeof(int), stream);   // cnt
    hist_kernel<<<(N_EDGES + BS - 1) / BS, BS, 0, stream>>>(dst, cursor);
    scan1_kernel<<<N_SCAN_BLOCKS, SCAN_BS, 0, stream>>>(cursor, partial, blocksum);
    scan2_kernel<<<1, SCAN_BS, 0, stream>>>(blocksum);
    scan3_kernel<<<(N_NODES + 1 + BS - 1) / BS, BS, 0, stream>>>(partial, blocksum, row_start, cursor);
    fill_kernel<<<(N_EDGES + BS - 1) / BS, BS, 0, stream>>>(dst, cursor, csr_eid);

    // Layer 0: 128 -> 128, ReLU
    run_layer<128, 128, 16, 16, 64, true>(x0, src, dst, W1, b1, xbuf1, h, w_e,
                                          nrminv, rowsum, degcnt, deg2, dinv, selfw,
                                          row_start, csr_eid, stream);
    // Layer 1: 128 -> 16, ReLU
    run_layer<128, 16, 16, 16, 16, true>(xbuf1, src, dst, W2, b2, xbuf2, h, w_e,
                                         nrminv, rowsum, degcnt, deg2, dinv, selfw,
                                         row_start, csr_eid, stream);
    // Layer 2: 16 -> 40, no ReLU
    run_layer<16, 40, 4, 4, 64, false>(xbuf2, src, dst, W3, b3, tmp3, h, w_e,
                                       nrminv, rowsum, degcnt, deg2, dinv, selfw,
                                       row_start, csr_eid, stream);

    logsoftmax_kernel<<<(N_NODES * 64 + 255) / 256, 256, 0, stream>>>(tmp3, out);
}

// Round 3
// 943.604 us; speedup vs baseline: 1.5846x; 1.5846x over previous
//
#include <hip/hip_runtime.h>
#include <math.h>

#define N_NODES 50000
#define N_EDGES 1600000
#define SCAN_BS 256
#define N_SCAN_BLOCKS ((N_NODES + SCAN_BS - 1) / SCAN_BS)   // 196

// ---------------- node inverse L2 norm: TPN lanes per node ----------------
template<int F, int TPN>
__global__ void norm_kernel(const float* __restrict__ x, float* __restrict__ nrminv) {
    int gid = blockIdx.x * blockDim.x + threadIdx.x;
    int node = gid / TPN;
    int t = gid % TPN;
    if (node >= N_NODES) return;
    const float* row = x + (size_t)node * F;
    float s = 0.f;
    constexpr int CHUNKS = F / (TPN * 4);
    #pragma unroll
    for (int c = 0; c < CHUNKS; c++) {
        float4 v = *(const float4*)(row + c * TPN * 4 + t * 4);
        s += v.x*v.x + v.y*v.y + v.z*v.z + v.w*v.w;
    }
    #pragma unroll
    for (int m = TPN/2; m >= 1; m >>= 1) s += __shfl_xor(s, m);
    if (t == 0) {
        float n = sqrtf(s);
        nrminv[node] = (n == 0.f) ? 1.f : 1.f / n;
    }
}

// =================== CSR-by-dst build (once per call) ===================
__global__ void hist_kernel(const int* __restrict__ dst, int* __restrict__ cnt) {
    int e = blockIdx.x * blockDim.x + threadIdx.x;
    if (e < N_EDGES) atomicAdd(&cnt[dst[e]], 1);
}

__global__ void scan1_kernel(const int* __restrict__ cnt, int* __restrict__ partial,
                             int* __restrict__ blocksum) {
    __shared__ int lds[SCAN_BS];
    int i = blockIdx.x * SCAN_BS + threadIdx.x;
    int v = (i < N_NODES) ? cnt[i] : 0;
    lds[threadIdx.x] = v;
    __syncthreads();
    for (int off = 1; off < SCAN_BS; off <<= 1) {
        int add = (threadIdx.x >= off) ? lds[threadIdx.x - off] : 0;
        __syncthreads();
        lds[threadIdx.x] += add;
        __syncthreads();
    }
    if (i < N_NODES) partial[i] = lds[threadIdx.x] - v;        // exclusive
    if (threadIdx.x == SCAN_BS - 1) blocksum[blockIdx.x] = lds[threadIdx.x];
}

__global__ void scan2_kernel(int* __restrict__ blocksum) {
    __shared__ int lds[SCAN_BS];
    int v = (threadIdx.x < N_SCAN_BLOCKS) ? blocksum[threadIdx.x] : 0;
    lds[threadIdx.x] = v;
    __syncthreads();
    for (int off = 1; off < SCAN_BS; off <<= 1) {
        int add = (threadIdx.x >= off) ? lds[threadIdx.x - off] : 0;
        __syncthreads();
        lds[threadIdx.x] += add;
        __syncthreads();
    }
    if (threadIdx.x < N_SCAN_BLOCKS) blocksum[threadIdx.x] = lds[threadIdx.x] - v;  // exclusive
}

__global__ void scan3_kernel(const int* __restrict__ partial, const int* __restrict__ blocksum,
                             int* __restrict__ row_start, int* __restrict__ cursor) {
    int i = blockIdx.x * blockDim.x + threadIdx.x;
    if (i < N_NODES) {
        int rs = partial[i] + blocksum[i / SCAN_BS];
        row_start[i] = rs;
        cursor[i] = rs;
    }
    if (i == N_NODES) row_start[N_NODES] = N_EDGES;
}

// fill: materialize edge data in CSR order (no eid indirection downstream)
__global__ void fill_kernel(const int* __restrict__ src, const int* __restrict__ dst,
                            int* __restrict__ cursor,
                            int* __restrict__ src_csr, int* __restrict__ dst_csr) {
    int e = blockIdx.x * blockDim.x + threadIdx.x;
    if (e < N_EDGES) {
        int d = dst[e];
        int pos = atomicAdd(&cursor[d], 1);
        src_csr[pos] = src[e];
        dst_csr[pos] = d;
    }
}

// ------------- per-edge cosine sim in CSR order; w_csr sequential write -------------
template<int F, int TPE>
__global__ void sim_csr_kernel(const float* __restrict__ x,
                               const float* __restrict__ nrminv,
                               const int* __restrict__ src_csr, const int* __restrict__ dst_csr,
                               float* __restrict__ w_csr,
                               float* __restrict__ rowsum, float* __restrict__ degcnt) {
    int gid = blockIdx.x * blockDim.x + threadIdx.x;
    int e = gid / TPE;
    int t = gid % TPE;
    if (e >= N_EDGES) return;
    int s = src_csr[e], d = dst_csr[e];
    const float* rs = x + (size_t)s * F;
    const float* rd = x + (size_t)d * F;   // consecutive e share d -> L1-hot
    float acc = 0.f;
    constexpr int CHUNKS = F / (TPE * 4);
    #pragma unroll
    for (int c = 0; c < CHUNKS; c++) {
        float4 a = *(const float4*)(rs + c * TPE * 4 + t * 4);
        float4 b = *(const float4*)(rd + c * TPE * 4 + t * 4);
        acc += a.x*b.x + a.y*b.y + a.z*b.z + a.w*b.w;
    }
    #pragma unroll
    for (int m = TPE/2; m >= 1; m >>= 1) acc += __shfl_xor(acc, m);
    if (t == 0) {
        float sim = acc * nrminv[s] * nrminv[d];
        float w = (s != d && sim >= 0.5f) ? sim : 0.f;
        w_csr[e] = w;
        if (w != 0.f) {
            atomicAdd(&rowsum[s], w);     // w >= 0.5 so |w| == w
            atomicAdd(&degcnt[s], 1.f);
        }
    }
}

// ------------- per node: L1-normalize row weights, deg2, dinv, selfw*dinv^2 -------------
template<int TPN>
__global__ void row_finalize_kernel(const int* __restrict__ row_start,
                                    const int* __restrict__ src_csr,
                                    const float* __restrict__ rowsum,
                                    const float* __restrict__ degcnt,
                                    float* __restrict__ w_csr,
                                    float* __restrict__ dinv, float* __restrict__ swd2) {
    int gid = blockIdx.x * blockDim.x + threadIdx.x;
    int node = gid / TPN;
    int t = gid % TPN;
    if (node >= N_NODES) return;
    int beg = row_start[node], end = row_start[node + 1];
    float sum = 0.f;
    for (int i = beg + t; i < end; i += TPN) {
        float w = w_csr[i];
        if (w != 0.f) {
            float wn = w / rowsum[src_csr[i]];   // rowsum >= w > 0 here
            w_csr[i] = wn;
            sum += wn;
        }
    }
    #pragma unroll
    for (int m = TPN/2; m >= 1; m >>= 1) sum += __shfl_xor(sum, m);
    if (t == 0) {
        float sw = 1.f / (degcnt[node] + 1.f);
        float dv = rsqrtf(sw + sum);             // deg2 = selfw + sum > 0 always
        dinv[node] = dv;
        swd2[node] = sw * dv * dv;
    }
}

// ------------- fold dinv[src] into w_csr: conv needs only (w', src, h) -------------
__global__ void scale_kernel(const int* __restrict__ src_csr, const float* __restrict__ dinv,
                             float* __restrict__ w_csr) {
    int e = blockIdx.x * blockDim.x + threadIdx.x;
    if (e >= N_EDGES) return;
    float w = w_csr[e];
    if (w != 0.f) w_csr[e] = w * dinv[src_csr[e]];
}

// ------------- h = x @ W  (W fully LDS-resident; thread computes 4 cols) -------------
template<int FIN, int FOUT>
__global__ void gemm_kernel(const float* __restrict__ x, const float* __restrict__ W,
                            float* __restrict__ h) {
    __shared__ float Wlds[FIN * FOUT];
    for (int i = threadIdx.x; i < FIN * FOUT; i += blockDim.x) Wlds[i] = W[i];
    __syncthreads();
    constexpr int C4 = FOUT / 4;
    int idx = blockIdx.x * blockDim.x + threadIdx.x;
    int row = idx / C4;
    int c4 = idx % C4;
    if (row >= N_NODES) return;
    const float* xr = x + (size_t)row * FIN;
    float4 acc = make_float4(0.f, 0.f, 0.f, 0.f);
    #pragma unroll 4
    for (int k = 0; k < FIN; k++) {
        float xv = xr[k];
        float4 w4 = *(const float4*)&Wlds[k * FOUT + c4 * 4];
        acc.x += xv * w4.x;
        acc.y += xv * w4.y;
        acc.z += xv * w4.z;
        acc.w += xv * w4.w;
    }
    *(float4*)&h[(size_t)row * FOUT + c4 * 4] = acc;
}

// ------------- gather conv, FOUT=128: TPN=32 lanes x float4; chunked shuffle
//               metadata -> up to 32 independent h-row gathers in flight -------------
template<bool RELU>
__global__ void conv_gather128_kernel(const int* __restrict__ row_start,
                                      const int* __restrict__ src_csr,
                                      const float* __restrict__ w_csr,
                                      const float* __restrict__ dinv,
                                      const float* __restrict__ swd2,
                                      const float* __restrict__ h,
                                      const float* __restrict__ b,
                                      float* __restrict__ out) {
    constexpr int TPN = 32;
    int gid = blockIdx.x * blockDim.x + threadIdx.x;
    int node = gid / TPN;
    int t = gid % TPN;
    if (node >= N_NODES) return;
    int beg = row_start[node], end = row_start[node + 1];
    float dv = dinv[node];
    float4 acc = make_float4(0.f, 0.f, 0.f, 0.f);
    for (int base = beg; base < end; base += TPN) {
        int i = base + t;
        float wv = (i < end) ? w_csr[i] : 0.f;
        int   sv = (i < end) ? src_csr[i] : 0;
        int cnt = end - base; if (cnt > TPN) cnt = TPN;
        #pragma unroll
        for (int j = 0; j < TPN; j++) {
            if (j >= cnt) break;
            float w = __shfl(wv, j, TPN);
            int   s = __shfl(sv, j, TPN);
            if (w != 0.f) {
                float coeff = w * dv;                 // dinv[s] pre-folded
                float4 hv = *(const float4*)(h + (size_t)s * 128 + t * 4);
                acc.x += coeff * hv.x; acc.y += coeff * hv.y;
                acc.z += coeff * hv.z; acc.w += coeff * hv.w;
            }
        }
    }
    float sd = swd2[node];
    float4 hv = *(const float4*)(h + (size_t)node * 128 + t * 4);
    float4 bv = *(const float4*)(b + t * 4);
    acc.x += sd * hv.x + bv.x; acc.y += sd * hv.y + bv.y;
    acc.z += sd * hv.z + bv.z; acc.w += sd * hv.w + bv.w;
    if (RELU) {
        acc.x = fmaxf(acc.x, 0.f); acc.y = fmaxf(acc.y, 0.f);
        acc.z = fmaxf(acc.z, 0.f); acc.w = fmaxf(acc.w, 0.f);
    }
    *(float4*)(out + (size_t)node * 128 + t * 4) = acc;
}

// ------------- gather conv, F=16: TPN=16 lanes x 1 float; optional bias/relu -------------
template<bool BIAS_RELU>
__global__ void conv_gather16_kernel(const int* __restrict__ row_start,
                                     const int* __restrict__ src_csr,
                                     const float* __restrict__ w_csr,
                                     const float* __restrict__ dinv,
                                     const float* __restrict__ swd2,
                                     const float* __restrict__ h,
                                     const float* __restrict__ b,
                                     float* __restrict__ out) {
    constexpr int TPN = 16;
    int gid = blockIdx.x * blockDim.x + threadIdx.x;
    int node = gid / TPN;
    int t = gid % TPN;
    if (node >= N_NODES) return;
    int beg = row_start[node], end = row_start[node + 1];
    float dv = dinv[node];
    float acc = 0.f;
    for (int base = beg; base < end; base += TPN) {
        int i = base + t;
        float wv = (i < end) ? w_csr[i] : 0.f;
        int   sv = (i < end) ? src_csr[i] : 0;
        int cnt = end - base; if (cnt > TPN) cnt = TPN;
        #pragma unroll
        for (int j = 0; j < TPN; j++) {
            if (j >= cnt) break;
            float w = __shfl(wv, j, TPN);
            int   s = __shfl(sv, j, TPN);
            if (w != 0.f) acc += (w * dv) * h[(size_t)s * 16 + t];
        }
    }
    float v = acc + swd2[node] * h[(size_t)node * 16 + t];
    if (BIAS_RELU) v = fmaxf(v + b[t], 0.f);
    out[(size_t)node * 16 + t] = v;
}

// ------------- fused: out40 = agg16 @ W3 + b3, then log_softmax. One wave/node. -------------
__global__ void final_kernel(const float* __restrict__ agg16,
                             const float* __restrict__ W3, const float* __restrict__ b3,
                             float* __restrict__ out) {
    __shared__ float Wl[16 * 40];
    __shared__ float bl[40];
    for (int i = threadIdx.x; i < 16 * 40; i += blockDim.x) Wl[i] = W3[i];
    if (threadIdx.x < 40) bl[threadIdx.x] = b3[threadIdx.x];
    __syncthreads();
    int wid = threadIdx.x / 64;
    int lane = threadIdx.x % 64;
    int v = blockIdx.x * 4 + wid;
    if (v >= N_NODES) return;
    const float* ar = agg16 + (size_t)v * 16;
    float o = -INFINITY;
    if (lane < 40) {
        o = bl[lane];
        #pragma unroll
        for (int k = 0; k < 16; k++) o += ar[k] * Wl[k * 40 + lane];
    }
    float m = o;
    #pragma unroll
    for (int s = 32; s >= 1; s >>= 1) m = fmaxf(m, __shfl_xor(m, s));
    float ex = (lane < 40) ? expf(o - m) : 0.f;
    float sum = ex;
    #pragma unroll
    for (int s = 32; s >= 1; s >>= 1) sum += __shfl_xor(sum, s);
    float lse = m + logf(sum);
    if (lane < 40) out[(size_t)v * 40 + lane] = o - lse;
}

// =================== host orchestration ===================
extern "C" void kernel_launch(void* const* d_in, const int* in_sizes, int n_in,
                              void* d_out, int out_size, void* d_ws, size_t ws_size,
                              hipStream_t stream) {
    const float* x0 = (const float*)d_in[0];
    const int* ei   = (const int*)d_in[1];
    const int* src  = ei;
    const int* dst  = ei + N_EDGES;
    const float* W1 = (const float*)d_in[2];
    const float* b1 = (const float*)d_in[3];
    const float* W2 = (const float*)d_in[4];
    const float* b2 = (const float*)d_in[5];
    const float* W3 = (const float*)d_in[6];
    const float* b3 = (const float*)d_in[7];
    float* out = (float*)d_out;

    // workspace layout: 15.45M floats + 3.35M ints ~= 75 MB
    float* ws     = (float*)d_ws;
    float* xbuf1  = ws;                        // 6,400,000 (layer-0 out, 50000x128)
    float* h      = xbuf1 + 6400000;           // 6,400,000 (h scratch; agg16 aliases front)
    float* w_csr  = h + 6400000;               // 1,600,000
    float* xbuf2  = w_csr + 1600000;           // 800,000 (layer-1 out, 50000x16)
    float* nrminv = xbuf2 + 800000;            // 50,000
    float* rowsum = nrminv + 50000;
    float* degcnt = rowsum + 50000;
    float* dinv   = degcnt + 50000;
    float* swd2   = dinv + 50000;
    int* iws       = (int*)(swd2 + 50000);
    int* row_start = iws;                      // 50,001
    int* cursor    = row_start + 50001;        // 50,000 (doubles as cnt)
    int* partial   = cursor + 50000;           // 50,000
    int* blocksum  = partial + 50000;          // 256
    int* src_csr   = blocksum + 256;           // 1,600,000
    int* dst_csr   = src_csr + N_EDGES;        // 1,600,000
    float* agg16   = h;                        // alias (50000x16)

    const int BS = 256;

    // ---- build CSR by dst (reused by all 3 layers) ----
    hipMemsetAsync(cursor, 0, N_NODES * sizeof(int), stream);
    hist_kernel<<<(N_EDGES + BS - 1) / BS, BS, 0, stream>>>(dst, cursor);
    scan1_kernel<<<N_SCAN_BLOCKS, SCAN_BS, 0, stream>>>(cursor, partial, blocksum);
    scan2_kernel<<<1, SCAN_BS, 0, stream>>>(blocksum);
    scan3_kernel<<<(N_NODES + 1 + BS - 1) / BS, BS, 0, stream>>>(partial, blocksum, row_start, cursor);
    fill_kernel<<<(N_EDGES + BS - 1) / BS, BS, 0, stream>>>(src, dst, cursor, src_csr, dst_csr);

    // ================= Layer 0: 128 -> 128, ReLU =================
    hipMemsetAsync(rowsum, 0, N_NODES * sizeof(float), stream);
    hipMemsetAsync(degcnt, 0, N_NODES * sizeof(float), stream);
    norm_kernel<128, 16><<<(N_NODES * 16 + BS - 1) / BS, BS, 0, stream>>>(x0, nrminv);
    sim_csr_kernel<128, 16><<<(int)(((long)N_EDGES * 16 + BS - 1) / BS), BS, 0, stream>>>(
        x0, nrminv, src_csr, dst_csr, w_csr, rowsum, degcnt);
    row_finalize_kernel<16><<<(N_NODES * 16 + BS - 1) / BS, BS, 0, stream>>>(
        row_start, src_csr, rowsum, degcnt, w_csr, dinv, swd2);
    scale_kernel<<<(N_EDGES + BS - 1) / BS, BS, 0, stream>>>(src_csr, dinv, w_csr);
    gemm_kernel<128, 128><<<(N_NODES * 32 + BS - 1) / BS, BS, 0, stream>>>(x0, W1, h);
    conv_gather128_kernel<true><<<(N_NODES * 32 + BS - 1) / BS, BS, 0, stream>>>(
        row_start, src_csr, w_csr, dinv, swd2, h, b1, xbuf1);

    // ================= Layer 1: 128 -> 16, ReLU =================
    hipMemsetAsync(rowsum, 0, N_NODES * sizeof(float), stream);
    hipMemsetAsync(degcnt, 0, N_NODES * sizeof(float), stream);
    norm_kernel<128, 16><<<(N_NODES * 16 + BS - 1) / BS, BS, 0, stream>>>(xbuf1, nrminv);
    sim_csr_kernel<128, 16><<<(int)(((long)N_EDGES * 16 + BS - 1) / BS), BS, 0, stream>>>(
        xbuf1, nrminv, src_csr, dst_csr, w_csr, rowsum, degcnt);
    row_finalize_kernel<16><<<(N_NODES * 16 + BS - 1) / BS, BS, 0, stream>>>(
        row_start, src_csr, rowsum, degcnt, w_csr, dinv, swd2);
    scale_kernel<<<(N_EDGES + BS - 1) / BS, BS, 0, stream>>>(src_csr, dinv, w_csr);
    gemm_kernel<128, 16><<<(N_NODES * 4 + BS - 1) / BS, BS, 0, stream>>>(xbuf1, W2, h);
    conv_gather16_kernel<true><<<(N_NODES * 16 + BS - 1) / BS, BS, 0, stream>>>(
        row_start, src_csr, w_csr, dinv, swd2, h, b2, xbuf2);

    // ================= Layer 2: 16 -> 40 (aggregate in x-space, then fused GEMM+LSM) ====
    hipMemsetAsync(rowsum, 0, N_NODES * sizeof(float), stream);
    hipMemsetAsync(degcnt, 0, N_NODES * sizeof(float), stream);
    norm_kernel<16, 4><<<(N_NODES * 4 + BS - 1) / BS, BS, 0, stream>>>(xbuf2, nrminv);
    sim_csr_kernel<16, 4><<<(int)(((long)N_EDGES * 4 + BS - 1) / BS), BS, 0, stream>>>(
        xbuf2, nrminv, src_csr, dst_csr, w_csr, rowsum, degcnt);
    row_finalize_kernel<16><<<(N_NODES * 16 + BS - 1) / BS, BS, 0, stream>>>(
        row_start, src_csr, rowsum, degcnt, w_csr, dinv, swd2);
    scale_kernel<<<(N_EDGES + BS - 1) / BS, BS, 0, stream>>>(src_csr, dinv, w_csr);
    conv_gather16_kernel<false><<<(N_NODES * 16 + BS - 1) / BS, BS, 0, stream>>>(
        row_start, src_csr, w_csr, dinv, swd2, xbuf2, b3 /*unused*/, agg16);
    final_kernel<<<(N_NODES + 3) / 4, BS, 0, stream>>>(agg16, W3, b3, out);
}

// Round 4
// 793.984 us; speedup vs baseline: 1.8832x; 1.1884x over previous
//
#include <hip/hip_runtime.h>
#include <math.h>

#define N_NODES 50000
#define N_EDGES 1600000
#define SCAN_BS 256
#define N_SCAN_BLOCKS ((N_NODES + SCAN_BS - 1) / SCAN_BS)   // 196

// ---------------- node inverse L2 norm (input layer only) ----------------
template<int F, int TPN>
__global__ void norm_kernel(const float* __restrict__ x, float* __restrict__ nrminv) {
    int gid = blockIdx.x * blockDim.x + threadIdx.x;
    int node = gid / TPN;
    int t = gid % TPN;
    if (node >= N_NODES) return;
    const float* row = x + (size_t)node * F;
    float s = 0.f;
    constexpr int CHUNKS = F / (TPN * 4);
    #pragma unroll
    for (int c = 0; c < CHUNKS; c++) {
        float4 v = *(const float4*)(row + c * TPN * 4 + t * 4);
        s += v.x*v.x + v.y*v.y + v.z*v.z + v.w*v.w;
    }
    #pragma unroll
    for (int m = TPN/2; m >= 1; m >>= 1) s += __shfl_xor(s, m);
    if (t == 0) {
        float n = sqrtf(s);
        nrminv[node] = (n == 0.f) ? 1.f : 1.f / n;
    }
}

// =================== CSR-by-dst build (once per call) ===================
__global__ void hist_kernel(const int* __restrict__ dst, int* __restrict__ cnt) {
    int e = blockIdx.x * blockDim.x + threadIdx.x;
    if (e < N_EDGES) atomicAdd(&cnt[dst[e]], 1);
}

__global__ void scan1_kernel(const int* __restrict__ cnt, int* __restrict__ partial,
                             int* __restrict__ blocksum) {
    __shared__ int lds[SCAN_BS];
    int i = blockIdx.x * SCAN_BS + threadIdx.x;
    int v = (i < N_NODES) ? cnt[i] : 0;
    lds[threadIdx.x] = v;
    __syncthreads();
    for (int off = 1; off < SCAN_BS; off <<= 1) {
        int add = (threadIdx.x >= off) ? lds[threadIdx.x - off] : 0;
        __syncthreads();
        lds[threadIdx.x] += add;
        __syncthreads();
    }
    if (i < N_NODES) partial[i] = lds[threadIdx.x] - v;        // exclusive
    if (threadIdx.x == SCAN_BS - 1) blocksum[blockIdx.x] = lds[threadIdx.x];
}

__global__ void scan2_kernel(int* __restrict__ blocksum) {
    __shared__ int lds[SCAN_BS];
    int v = (threadIdx.x < N_SCAN_BLOCKS) ? blocksum[threadIdx.x] : 0;
    lds[threadIdx.x] = v;
    __syncthreads();
    for (int off = 1; off < SCAN_BS; off <<= 1) {
        int add = (threadIdx.x >= off) ? lds[threadIdx.x - off] : 0;
        __syncthreads();
        lds[threadIdx.x] += add;
        __syncthreads();
    }
    if (threadIdx.x < N_SCAN_BLOCKS) blocksum[threadIdx.x] = lds[threadIdx.x] - v;  // exclusive
}

__global__ void scan3_kernel(const int* __restrict__ partial, const int* __restrict__ blocksum,
                             int* __restrict__ row_start, int* __restrict__ cursor) {
    int i = blockIdx.x * blockDim.x + threadIdx.x;
    if (i < N_NODES) {
        int rs = partial[i] + blocksum[i / SCAN_BS];
        row_start[i] = rs;
        cursor[i] = rs;
    }
    if (i == N_NODES) row_start[N_NODES] = N_EDGES;
}

__global__ void fill_kernel(const int* __restrict__ src, const int* __restrict__ dst,
                            int* __restrict__ cursor,
                            int* __restrict__ src_csr, int* __restrict__ dst_csr) {
    int e = blockIdx.x * blockDim.x + threadIdx.x;
    if (e < N_EDGES) {
        int d = dst[e];
        int pos = atomicAdd(&cursor[d], 1);
        src_csr[pos] = src[e];
        dst_csr[pos] = d;
    }
}

// ------------- per-edge cosine sim in CSR order -------------
template<int F, int TPE>
__global__ void sim_csr_kernel(const float* __restrict__ x,
                               const float* __restrict__ nrminv,
                               const int* __restrict__ src_csr, const int* __restrict__ dst_csr,
                               float* __restrict__ w_csr,
                               float* __restrict__ rowsum, float* __restrict__ degcnt) {
    int gid = blockIdx.x * blockDim.x + threadIdx.x;
    int e = gid / TPE;
    int t = gid % TPE;
    if (e >= N_EDGES) return;
    int s = src_csr[e], d = dst_csr[e];
    const float* rs = x + (size_t)s * F;
    const float* rd = x + (size_t)d * F;   // consecutive e share d -> L1-hot
    float acc = 0.f;
    constexpr int CHUNKS = F / (TPE * 4);
    #pragma unroll
    for (int c = 0; c < CHUNKS; c++) {
        float4 a = *(const float4*)(rs + c * TPE * 4 + t * 4);
        float4 b = *(const float4*)(rd + c * TPE * 4 + t * 4);
        acc += a.x*b.x + a.y*b.y + a.z*b.z + a.w*b.w;
    }
    #pragma unroll
    for (int m = TPE/2; m >= 1; m >>= 1) acc += __shfl_xor(acc, m);
    if (t == 0) {
        float sim = acc * nrminv[s] * nrminv[d];
        float w = (s != d && sim >= 0.5f) ? sim : 0.f;
        w_csr[e] = w;
        if (w != 0.f) {
            atomicAdd(&rowsum[s], w);     // w >= 0.5 so |w| == w
            atomicAdd(&degcnt[s], 1.f);
        }
    }
}

// ------------- per node: L1-normalize row weights, dinv, selfw*dinv^2 -------------
template<int TPN>
__global__ void row_finalize_kernel(const int* __restrict__ row_start,
                                    const int* __restrict__ src_csr,
                                    const float* __restrict__ rowsum,
                                    const float* __restrict__ degcnt,
                                    float* __restrict__ w_csr,
                                    float* __restrict__ dinv, float* __restrict__ swd2) {
    int gid = blockIdx.x * blockDim.x + threadIdx.x;
    int node = gid / TPN;
    int t = gid % TPN;
    if (node >= N_NODES) return;
    int beg = row_start[node], end = row_start[node + 1];
    float sum = 0.f;
    for (int i = beg + t; i < end; i += TPN) {
        float w = w_csr[i];
        if (w != 0.f) {
            float wn = w / rowsum[src_csr[i]];   // rowsum >= w > 0 here
            w_csr[i] = wn;
            sum += wn;
        }
    }
    #pragma unroll
    for (int m = TPN/2; m >= 1; m >>= 1) sum += __shfl_xor(sum, m);
    if (t == 0) {
        float sw = 1.f / (degcnt[node] + 1.f);
        float dv = rsqrtf(sw + sum);             // deg2 = selfw + sum > 0 always
        dinv[node] = dv;
        swd2[node] = sw * dv * dv;
    }
}

// ------------- tiled fp32 GEMM: h = x @ W, x:[N][FIN], W:[FIN][FOUT] -------------
// block = 256 threads computes TM x FOUT tile; KC k-chunk staged in LDS.
// RPT rows/thread (consecutive, b128 LDS reads), CPT cols/thread (4 -> float4 W).
template<int FIN, int FOUT, int TM, int KC, int RPT, int CPT>
__global__ __launch_bounds__(256) void gemm_tiled(const float* __restrict__ x,
                                                  const float* __restrict__ W,
                                                  float* __restrict__ h) {
    constexpr int COLG = FOUT / CPT;           // col groups
    static_assert(COLG * (TM / RPT) == 256, "thread mapping");
    __shared__ float xT[KC][TM];               // transposed x tile
    __shared__ float Wl[KC][FOUT];
    int tid = threadIdx.x;
    int row0 = blockIdx.x * TM;
    int c0 = (tid % COLG) * CPT;
    int r0 = (tid / COLG) * RPT;
    float acc[RPT][CPT];
    #pragma unroll
    for (int r = 0; r < RPT; r++)
        #pragma unroll
        for (int c = 0; c < CPT; c++) acc[r][c] = 0.f;

    for (int kc = 0; kc < FIN; kc += KC) {
        // stage x tile transposed: TM*KC floats via float4 along k
        constexpr int SLOTS_PER_ROW = KC / 4;
        constexpr int XQ = TM * KC / (256 * 4);
        #pragma unroll
        for (int j = 0; j < XQ; j++) {
            int idx = tid + j * 256;
            int tr = idx / SLOTS_PER_ROW;
            int tk = (idx % SLOTS_PER_ROW) * 4;
            int grow = row0 + tr;
            float4 v = make_float4(0.f, 0.f, 0.f, 0.f);
            if (grow < N_NODES) v = *(const float4*)(x + (size_t)grow * FIN + kc + tk);
            xT[tk + 0][tr] = v.x; xT[tk + 1][tr] = v.y;
            xT[tk + 2][tr] = v.z; xT[tk + 3][tr] = v.w;
        }
        // stage W chunk: KC*FOUT floats
        if constexpr (KC * FOUT >= 1024) {
            constexpr int WQ = KC * FOUT / (256 * 4);
            #pragma unroll
            for (int j = 0; j < WQ; j++) {
                int idx = tid + j * 256;
                int wk = idx / (FOUT / 4);
                int wc = (idx % (FOUT / 4)) * 4;
                *(float4*)&Wl[wk][wc] = *(const float4*)(W + (size_t)(kc + wk) * FOUT + wc);
            }
        } else {
            // KC*FOUT == 256
            Wl[tid / FOUT][tid % FOUT] = W[(size_t)(kc + tid / FOUT) * FOUT + tid % FOUT];
        }
        __syncthreads();

        #pragma unroll
        for (int k = 0; k < KC; k++) {
            float a[RPT];
            #pragma unroll
            for (int rr = 0; rr < RPT; rr += 4) {
                float4 xv = *(const float4*)&xT[k][r0 + rr];
                a[rr] = xv.x; a[rr+1] = xv.y; a[rr+2] = xv.z; a[rr+3] = xv.w;
            }
            if constexpr (CPT == 4) {
                float4 wv = *(const float4*)&Wl[k][c0];
                #pragma unroll
                for (int rr = 0; rr < RPT; rr++) {
                    acc[rr][0] += a[rr] * wv.x; acc[rr][1] += a[rr] * wv.y;
                    acc[rr][2] += a[rr] * wv.z; acc[rr][3] += a[rr] * wv.w;
                }
            } else {
                float wv = Wl[k][c0];
                #pragma unroll
                for (int rr = 0; rr < RPT; rr++) acc[rr][0] += a[rr] * wv;
            }
        }
        __syncthreads();
    }

    #pragma unroll
    for (int rr = 0; rr < RPT; rr++) {
        int grow = row0 + r0 + rr;
        if (grow < N_NODES) {
            if constexpr (CPT == 4) {
                float4 o = make_float4(acc[rr][0], acc[rr][1], acc[rr][2], acc[rr][3]);
                *(float4*)(h + (size_t)grow * FOUT + c0) = o;
            } else {
                h[(size_t)grow * FOUT + c0] = acc[rr][0];
            }
        }
    }
}

// ------------- gather conv FOUT=128; dinv[src] folded at metadata load;
//               optionally writes next layer's nrminv (row is in-register) -------------
template<bool RELU, bool WNORM>
__global__ void conv_gather128_kernel(const int* __restrict__ row_start,
                                      const int* __restrict__ src_csr,
                                      const float* __restrict__ w_csr,
                                      const float* __restrict__ dinv,
                                      const float* __restrict__ swd2,
                                      const float* __restrict__ h,
                                      const float* __restrict__ b,
                                      float* __restrict__ out,
                                      float* __restrict__ nrminv_out) {
    constexpr int TPN = 32;
    int gid = blockIdx.x * blockDim.x + threadIdx.x;
    int node = gid / TPN;
    int t = gid % TPN;
    if (node >= N_NODES) return;
    int beg = row_start[node], end = row_start[node + 1];
    float dv = dinv[node];
    float4 acc = make_float4(0.f, 0.f, 0.f, 0.f);
    for (int base = beg; base < end; base += TPN) {
        int i = base + t;
        float wv = 0.f; int sv = 0;
        if (i < end) {
            wv = w_csr[i];
            sv = src_csr[i];
            if (wv != 0.f) wv *= dinv[sv];       // fold dinv[src]
        }
        int cnt = end - base; if (cnt > TPN) cnt = TPN;
        #pragma unroll
        for (int j = 0; j < TPN; j++) {
            if (j >= cnt) break;
            float w = __shfl(wv, j, TPN);
            int   s = __shfl(sv, j, TPN);
            if (w != 0.f) {
                float coeff = w * dv;
                float4 hv = *(const float4*)(h + (size_t)s * 128 + t * 4);
                acc.x += coeff * hv.x; acc.y += coeff * hv.y;
                acc.z += coeff * hv.z; acc.w += coeff * hv.w;
            }
        }
    }
    float sd = swd2[node];
    float4 hv = *(const float4*)(h + (size_t)node * 128 + t * 4);
    float4 bv = *(const float4*)(b + t * 4);
    acc.x += sd * hv.x + bv.x; acc.y += sd * hv.y + bv.y;
    acc.z += sd * hv.z + bv.z; acc.w += sd * hv.w + bv.w;
    if (RELU) {
        acc.x = fmaxf(acc.x, 0.f); acc.y = fmaxf(acc.y, 0.f);
        acc.z = fmaxf(acc.z, 0.f); acc.w = fmaxf(acc.w, 0.f);
    }
    *(float4*)(out + (size_t)node * 128 + t * 4) = acc;
    if (WNORM) {
        float ss = acc.x*acc.x + acc.y*acc.y + acc.z*acc.z + acc.w*acc.w;
        #pragma unroll
        for (int m = TPN/2; m >= 1; m >>= 1) ss += __shfl_xor(ss, m);
        if (t == 0) {
            float n = sqrtf(ss);
            nrminv_out[node] = (n == 0.f) ? 1.f : 1.f / n;
        }
    }
}

// ------------- gather conv F=16; same folding/fusion -------------
template<bool BIAS_RELU, bool WNORM>
__global__ void conv_gather16_kernel(const int* __restrict__ row_start,
                                     const int* __restrict__ src_csr,
                                     const float* __restrict__ w_csr,
                                     const float* __restrict__ dinv,
                                     const float* __restrict__ swd2,
                                     const float* __restrict__ h,
                                     const float* __restrict__ b,
                                     float* __restrict__ out,
                                     float* __restrict__ nrminv_out) {
    constexpr int TPN = 16;
    int gid = blockIdx.x * blockDim.x + threadIdx.x;
    int node = gid / TPN;
    int t = gid % TPN;
    if (node >= N_NODES) return;
    int beg = row_start[node], end = row_start[node + 1];
    float dv = dinv[node];
    float acc = 0.f;
    for (int base = beg; base < end; base += TPN) {
        int i = base + t;
        float wv = 0.f; int sv = 0;
        if (i < end) {
            wv = w_csr[i];
            sv = src_csr[i];
            if (wv != 0.f) wv *= dinv[sv];
        }
        int cnt = end - base; if (cnt > TPN) cnt = TPN;
        #pragma unroll
        for (int j = 0; j < TPN; j++) {
            if (j >= cnt) break;
            float w = __shfl(wv, j, TPN);
            int   s = __shfl(sv, j, TPN);
            if (w != 0.f) acc += (w * dv) * h[(size_t)s * 16 + t];
        }
    }
    float v = acc + swd2[node] * h[(size_t)node * 16 + t];
    if (BIAS_RELU) v = fmaxf(v + b[t], 0.f);
    out[(size_t)node * 16 + t] = v;
    if (WNORM) {
        float ss = v * v;
        #pragma unroll
        for (int m = TPN/2; m >= 1; m >>= 1) ss += __shfl_xor(ss, m);
        if (t == 0) {
            float n = sqrtf(ss);
            nrminv_out[node] = (n == 0.f) ? 1.f : 1.f / n;
        }
    }
}

// ------------- fused: out40 = agg16 @ W3 + b3, then log_softmax. One wave/node. -------------
__global__ void final_kernel(const float* __restrict__ agg16,
                             const float* __restrict__ W3, const float* __restrict__ b3,
                             float* __restrict__ out) {
    __shared__ float Wl[16 * 40];
    __shared__ float bl[40];
    for (int i = threadIdx.x; i < 16 * 40; i += blockDim.x) Wl[i] = W3[i];
    if (threadIdx.x < 40) bl[threadIdx.x] = b3[threadIdx.x];
    __syncthreads();
    int wid = threadIdx.x / 64;
    int lane = threadIdx.x % 64;
    int v = blockIdx.x * 4 + wid;
    if (v >= N_NODES) return;
    const float* ar = agg16 + (size_t)v * 16;
    float o = -INFINITY;
    if (lane < 40) {
        o = bl[lane];
        #pragma unroll
        for (int k = 0; k < 16; k++) o += ar[k] * Wl[k * 40 + lane];
    }
    float m = o;
    #pragma unroll
    for (int s = 32; s >= 1; s >>= 1) m = fmaxf(m, __shfl_xor(m, s));
    float ex = (lane < 40) ? expf(o - m) : 0.f;
    float sum = ex;
    #pragma unroll
    for (int s = 32; s >= 1; s >>= 1) sum += __shfl_xor(sum, s);
    float lse = m + logf(sum);
    if (lane < 40) out[(size_t)v * 40 + lane] = o - lse;
}

// =================== host orchestration ===================
extern "C" void kernel_launch(void* const* d_in, const int* in_sizes, int n_in,
                              void* d_out, int out_size, void* d_ws, size_t ws_size,
                              hipStream_t stream) {
    const float* x0 = (const float*)d_in[0];
    const int* ei   = (const int*)d_in[1];
    const int* src  = ei;
    const int* dst  = ei + N_EDGES;
    const float* W1 = (const float*)d_in[2];
    const float* b1 = (const float*)d_in[3];
    const float* W2 = (const float*)d_in[4];
    const float* b2 = (const float*)d_in[5];
    const float* W3 = (const float*)d_in[6];
    const float* b3 = (const float*)d_in[7];
    float* out = (float*)d_out;

    float* ws     = (float*)d_ws;
    float* xbuf1  = ws;                        // 6,400,000 (layer-0 out, 50000x128)
    float* h      = xbuf1 + 6400000;           // 6,400,000 (h scratch; agg16 aliases front)
    float* w_csr  = h + 6400000;               // 1,600,000
    float* xbuf2  = w_csr + 1600000;           // 800,000 (layer-1 out, 50000x16)
    float* nrminv = xbuf2 + 800000;            // 50,000
    float* rowsum = nrminv + 50000;            // 50,000  (rowsum+degcnt = one memset)
    float* degcnt = rowsum + 50000;            // 50,000
    float* dinv   = degcnt + 50000;
    float* swd2   = dinv + 50000;
    int* iws       = (int*)(swd2 + 50000);
    int* row_start = iws;                      // 50,001
    int* cursor    = row_start + 50001;        // 50,000 (doubles as cnt)
    int* partial   = cursor + 50000;           // 50,000
    int* blocksum  = partial + 50000;          // 256
    int* src_csr   = blocksum + 256;           // 1,600,000
    int* dst_csr   = src_csr + N_EDGES;        // 1,600,000
    float* agg16   = h;                        // alias (50000x16)

    const int BS = 256;

    // ---- build CSR by dst (reused by all 3 layers) ----
    hipMemsetAsync(cursor, 0, N_NODES * sizeof(int), stream);
    hist_kernel<<<(N_EDGES + BS - 1) / BS, BS, 0, stream>>>(dst, cursor);
    scan1_kernel<<<N_SCAN_BLOCKS, SCAN_BS, 0, stream>>>(cursor, partial, blocksum);
    scan2_kernel<<<1, SCAN_BS, 0, stream>>>(blocksum);
    scan3_kernel<<<(N_NODES + 1 + BS - 1) / BS, BS, 0, stream>>>(partial, blocksum, row_start, cursor);
    fill_kernel<<<(N_EDGES + BS - 1) / BS, BS, 0, stream>>>(src, dst, cursor, src_csr, dst_csr);

    // ================= Layer 0: 128 -> 128, ReLU =================
    hipMemsetAsync(rowsum, 0, 2 * N_NODES * sizeof(float), stream);   // rowsum+degcnt
    norm_kernel<128, 16><<<(N_NODES * 16 + BS - 1) / BS, BS, 0, stream>>>(x0, nrminv);
    sim_csr_kernel<128, 16><<<(int)(((long)N_EDGES * 16 + BS - 1) / BS), BS, 0, stream>>>(
        x0, nrminv, src_csr, dst_csr, w_csr, rowsum, degcnt);
    row_finalize_kernel<16><<<(N_NODES * 16 + BS - 1) / BS, BS, 0, stream>>>(
        row_start, src_csr, rowsum, degcnt, w_csr, dinv, swd2);
    gemm_tiled<128, 128, 64, 16, 8, 4><<<(N_NODES + 63) / 64, BS, 0, stream>>>(x0, W1, h);
    conv_gather128_kernel<true, true><<<(N_NODES * 32 + BS - 1) / BS, BS, 0, stream>>>(
        row_start, src_csr, w_csr, dinv, swd2, h, b1, xbuf1, nrminv);

    // ================= Layer 1: 128 -> 16, ReLU =================
    hipMemsetAsync(rowsum, 0, 2 * N_NODES * sizeof(float), stream);
    sim_csr_kernel<128, 16><<<(int)(((long)N_EDGES * 16 + BS - 1) / BS), BS, 0, stream>>>(
        xbuf1, nrminv, src_csr, dst_csr, w_csr, rowsum, degcnt);
    row_finalize_kernel<16><<<(N_NODES * 16 + BS - 1) / BS, BS, 0, stream>>>(
        row_start, src_csr, rowsum, degcnt, w_csr, dinv, swd2);
    gemm_tiled<128, 16, 128, 16, 8, 1><<<(N_NODES + 127) / 128, BS, 0, stream>>>(xbuf1, W2, h);
    conv_gather16_kernel<true, true><<<(N_NODES * 16 + BS - 1) / BS, BS, 0, stream>>>(
        row_start, src_csr, w_csr, dinv, swd2, h, b2, xbuf2, nrminv);

    // ========== Layer 2: 16 -> 40 (aggregate in x-space, then fused GEMM+LSM) ==========
    hipMemsetAsync(rowsum, 0, 2 * N_NODES * sizeof(float), stream);
    sim_csr_kernel<16, 4><<<(int)(((long)N_EDGES * 4 + BS - 1) / BS), BS, 0, stream>>>(
        xbuf2, nrminv, src_csr, dst_csr, w_csr, rowsum, degcnt);
    row_finalize_kernel<16><<<(N_NODES * 16 + BS - 1) / BS, BS, 0, stream>>>(
        row_start, src_csr, rowsum, degcnt, w_csr, dinv, swd2);
    conv_gather16_kernel<false, false><<<(N_NODES * 16 + BS - 1) / BS, BS, 0, stream>>>(
        row_start, src_csr, w_csr, dinv, swd2, xbuf2, b3 /*unused*/, agg16, nullptr);
    final_kernel<<<(N_NODES + 3) / 4, BS, 0, stream>>>(agg16, W3, b3, out);
}